// Round 11
// baseline (591.737 us; speedup 1.0000x reference)
//
#include <hip/hip_runtime.h>
#include <hip/hip_bf16.h>

typedef __bf16 bf16_t;
typedef __bf16 bf16x8 __attribute__((ext_vector_type(8)));
typedef float f32x4 __attribute__((ext_vector_type(4)));

#define B_  4
#define S_  2048
#define H_  16
#define DK_ 128
#define DM_ 2048
#define BS_ (B_ * S_)          // 8192 rows

static __device__ __forceinline__ f32x4 mfma16(bf16x8 a, bf16x8 b, f32x4 c) {
  return __builtin_amdgcn_mfma_f32_16x16x32_bf16(a, b, c, 0, 0, 0);
}

// async global->LDS 16B copy. lds base must be wave-uniform; HW scatters lane*16.
static __device__ __forceinline__ void async_copy16(const bf16_t* g, bf16_t* l) {
  __builtin_amdgcn_global_load_lds(
      (const __attribute__((address_space(1))) void*)g,
      (__attribute__((address_space(3))) void*)l, 16, 0, 0);
}

// raw workgroup barrier WITHOUT the vmcnt(0)/lgkmcnt(0) drain __syncthreads
// emits; "memory" clobber = compiler fence.
#define BARRIER() asm volatile("s_barrier" ::: "memory")
#define WAIT_VM4() asm volatile("s_waitcnt vmcnt(4)" ::: "memory")

// DPP row_ror (within 16-lane row) on f32 -- cross-lane reduce on the VALU pipe.
template <int CTRL>
static __device__ __forceinline__ float dpp_rorf(float x) {
  return __builtin_bit_cast(float,
      __builtin_amdgcn_update_dpp(0, __builtin_bit_cast(int, x), CTRL, 0xF, 0xF, true));
}
static __device__ __forceinline__ float rowmax16(float r) {
  r = fmaxf(r, dpp_rorf<0x121>(r));
  r = fmaxf(r, dpp_rorf<0x122>(r));
  r = fmaxf(r, dpp_rorf<0x124>(r));
  r = fmaxf(r, dpp_rorf<0x128>(r));
  return r;
}
static __device__ __forceinline__ float rowsum16(float r) {
  r += dpp_rorf<0x121>(r);
  r += dpp_rorf<0x122>(r);
  r += dpp_rorf<0x124>(r);
  r += dpp_rorf<0x128>(r);
  return r;
}

struct ChainOn  { static constexpr bool v = true;  };
struct ChainOff { static constexpr bool v = false; };

// ---------------------------------------------------------------------------
// fp32 -> bf16 elementwise convert (8 elems/thread)
// ---------------------------------------------------------------------------
__global__ __launch_bounds__(256) void cvt_bf16(const float* __restrict__ in,
                                                bf16_t* __restrict__ out, int n8) {
  int i = blockIdx.x * 256 + threadIdx.x;
  if (i < n8) {
    const float4* p = (const float4*)in + (size_t)i * 2;
    float4 f0 = p[0], f1 = p[1];
    bf16x8 r;
    r[0] = (bf16_t)f0.x; r[1] = (bf16_t)f0.y; r[2] = (bf16_t)f0.z; r[3] = (bf16_t)f0.w;
    r[4] = (bf16_t)f1.x; r[5] = (bf16_t)f1.y; r[6] = (bf16_t)f1.z; r[7] = (bf16_t)f1.w;
    ((bf16x8*)out)[i] = r;
  }
}

// ---------------------------------------------------------------------------
// GEMM body: C[M,N] = A[M,K] * B[N,K]^T, 256x256 tile, 8 waves (2Mx4N).
// r10 post-mortem: reads still COMPLETE inside the barrier-boxed phase that
// consumes them -> DS pipe (~1150cyc/K32-pair) serializes with MFMA
// (~1240cyc) -> 3000cyc/pair, MfmaUtil 38%. Fix: cross-phase fragment
// pipelining. 4 superphases/iter (s1..s4 = halves (0,0),(0,1),(1,0),(1,1)),
// each:
//   top:  read af1 (own half, mh1 rows)     -> drains under mma-mh0
//         stage 1 half-pair (A+B, 4 loads)
//   BAR1; mma-mh0 on bank c (af0/bf read MID-PREVIOUS superphase: lgkm free)
//   mid:  read next half's af0/bf into bank 1-c  -> drains under mma-mh1 +
//         next superphase's mma-mh0
//   mma-mh1 (af1 long drained); WAIT vmcnt(4); BAR2
// Every ds_read completes under an MFMA cluster; barrier count halved.
//
// Ledger (4 loads/sp FIFO; stages s1:(1,1)<-o s2:(0,0)<-e+2 s3:(0,1)<-e+2
// s4:(1,0)<-o+2; mid-reads s1:(0,1) s2:(1,0) s3:(1,1) s4:(0,0)<-e'):
//  end-s1 vmcnt(4): outstanding {s4(I-1),s1} -> drains (1,0)<-o  [mid-s2] OK
//  end-s2: {s1,s2} -> drains (1,1)<-o   [mid-s3] OK
//  end-s3: {s2,s3} -> drains (0,0)<-e+2 [mid-s4] OK
//  end-s4: {s3,s4} -> drains (0,1)<-e+2 [mid-s1(I+1)] OK
//  Flight >= 1.5 superphases (~2K cyc) >> HBM ~900. Each wait precedes BAR2,
//  so all waves' loads are confirmed before any wave's dependent read.
// Overwrite safety (all 8 entries): each stage's target half had its last
// reads (top-af1 / mid-af0,bf) lgkm-retire before the mma that consumes
// them, which precedes the BAR2 before the stage issues.
// Prologue: stage (0,0),(0,1),(1,0); vmcnt(8) [=(0,0) ready]; read bank0;
// vmcnt(4) [=(0,1) ready]; barrier -> enters loop in steady state.
// Tail: clamped stages/reads into dead slots; final vmcnt(0) before epilogue.
// Swizzle (refcheck'd r6-r10): chunk q of row r at physical q ^ s(r),
// s(r)=(r+(r>>2))&3; LDS dest linear for global_load_lds; SOURCE chunk
// inverse-swizzled; ds_read applies the XOR (lane-only for 16-aligned rows).
// Saddr form: uniform base (A + bm*K) + 32-bit per-lane offset saves VGPRs.
// vtout: write C per-head-transposed into Vt layout [(b*16+h)*128+d][s].
// ---------------------------------------------------------------------------
template <typename TC>
static __device__ __forceinline__ void gemm_body(
    const bf16_t* __restrict__ A, const bf16_t* __restrict__ B, TC* __restrict__ C,
    bool vtout, int b256, bf16_t (&Ab)[2][2][8192], bf16_t (&Bb)[2][2][8192]) {
  const int tid  = threadIdx.x;
  const int wave = tid >> 6;              // 0..7
  const int lane = tid & 63;
  const int quad = lane >> 4;
  const int l16  = lane & 15;
  const int wm   = (wave >> 2) * 128;     // wave's M half
  const int wn   = (wave & 3) * 64;       // wave's N quarter

  // XCD-bijective remap: 256 blocks; each xcd owns a contiguous 4x8 stripe.
  const int xcd = b256 & 7;
  const int idx = b256 >> 3;              // 0..31
  const int bm  = (xcd * 4 + (idx >> 3)) * 256;
  const int bn  = (idx & 7) * 256;
  const int K   = DM_;

  // uniform bases (SGPR) + 32-bit per-lane offsets (1 VGPR each)
  const bf16_t* Ablk = A + (size_t)bm * (size_t)K;
  const bf16_t* Bblk = B + (size_t)bn * (size_t)K;
  const int r0  = wave * 16 + (lane >> 2);
  const int r1  = r0 + 128;
  const int sz0 = (r0 + (r0 >> 2)) & 3;
  const int sz1 = (r1 + (r1 >> 2)) & 3;
  const int o0  = r0 * K + (((lane & 3) ^ sz0) * 8);
  const int o1  = r1 * K + (((lane & 3) ^ sz1) * 8);
  const int dst0 = wave * 512;            // wave-uniform LDS elem offsets
  const int dst1 = 4096 + wave * 512;

  // stage one half-pair: A and B halves of (buf,kh) from K-tile kt. 4 loads.
  auto stg = [&](int buf, int kh, int kt) __attribute__((always_inline)) {
    const int c = kt * 64 + kh * 32;
    async_copy16(Ablk + o0 + c, &Ab[buf][kh][dst0]);
    async_copy16(Ablk + o1 + c, &Ab[buf][kh][dst1]);
    async_copy16(Bblk + o0 + c, &Bb[buf][kh][dst0]);
    async_copy16(Bblk + o1 + c, &Bb[buf][kh][dst1]);
  };

  // fragment-read swizzle (lane-only: row bases are 16-aligned)
  const int sw = (l16 + (l16 >> 2)) & 3;
  const int qs = (quad ^ sw) * 8;

  f32x4 acc[8][4];
#pragma unroll
  for (int i = 0; i < 8; ++i)
#pragma unroll
    for (int j = 0; j < 4; ++j) acc[i][j] = (f32x4){0.f, 0.f, 0.f, 0.f};

  // double-banked fragments (bank indices compile-time after inlining)
  bf16x8 af0[2][4], bf[2][4], af1[4];

  auto rdA0 = [&](int bank, int buf, int kh) __attribute__((always_inline)) {
#pragma unroll
    for (int i = 0; i < 4; ++i)
      af0[bank][i] = *(const bf16x8*)(&Ab[buf][kh][(wm + i * 16 + l16) * 32 + qs]);
  };
  auto rdA1 = [&](int buf, int kh) __attribute__((always_inline)) {
#pragma unroll
    for (int i = 0; i < 4; ++i)
      af1[i] = *(const bf16x8*)(&Ab[buf][kh][(wm + 64 + i * 16 + l16) * 32 + qs]);
  };
  auto rdB = [&](int bank, int buf, int kh) __attribute__((always_inline)) {
#pragma unroll
    for (int n = 0; n < 4; ++n)
      bf[bank][n] = *(const bf16x8*)(&Bb[buf][kh][(wn + n * 16 + l16) * 32 + qs]);
  };
  auto mma0 = [&](int bank) __attribute__((always_inline)) {
    __builtin_amdgcn_s_setprio(1);
#pragma unroll
    for (int i = 0; i < 4; ++i)
#pragma unroll
      for (int n = 0; n < 4; ++n)
        acc[i][n] = mfma16(af0[bank][i], bf[bank][n], acc[i][n]);
    __builtin_amdgcn_s_setprio(0);
  };
  auto mma1 = [&](int bank) __attribute__((always_inline)) {
    __builtin_amdgcn_s_setprio(1);
#pragma unroll
    for (int i = 0; i < 4; ++i)
#pragma unroll
      for (int n = 0; n < 4; ++n)
        acc[4 + i][n] = mfma16(af1[i], bf[bank][n], acc[4 + i][n]);
    __builtin_amdgcn_s_setprio(0);
  };

  const int NT = K >> 6;                  // 32 K-tiles (BK=64)

  // prologue: (0,0)<-t0, (0,1)<-t0, (1,0)<-t1 staged; bank0 prefilled.
  stg(0, 0, 0); stg(0, 1, 0); stg(1, 0, 1);
  asm volatile("s_waitcnt vmcnt(8)" ::: "memory");   // (0,0) resident
  BARRIER();
  rdA0(0, 0, 0); rdB(0, 0, 0);
  asm volatile("s_waitcnt vmcnt(4)" ::: "memory");   // (0,1) resident
  BARRIER();                                         // publish before mid-s1

  for (int I = 0; I < (NT >> 1); ++I) {
    const int o   = 2 * I + 1;
    const int te2 = (2 * I + 2 < NT) ? 2 * I + 2 : NT - 1;  // clamped tail
    const int to2 = (2 * I + 3 < NT) ? 2 * I + 3 : NT - 1;

    // s1: consume bank0 = (0,0)=e.kh0 | fill bank1 <- (0,1) | stage (1,1)<-o
    rdA1(0, 0);
    stg(1, 1, o);
    BARRIER();
    mma0(0);
    rdA0(1, 0, 1); rdB(1, 0, 1);
    mma1(0);
    WAIT_VM4();
    BARRIER();
    // s2: consume bank1 = (0,1)=e.kh1 | fill bank0 <- (1,0) | stage (0,0)<-e+2
    rdA1(0, 1);
    stg(0, 0, te2);
    BARRIER();
    mma0(1);
    rdA0(0, 1, 0); rdB(0, 1, 0);
    mma1(1);
    WAIT_VM4();
    BARRIER();
    // s3: consume bank0 = (1,0)=o.kh0 | fill bank1 <- (1,1) | stage (0,1)<-e+2
    rdA1(1, 0);
    stg(0, 1, te2);
    BARRIER();
    mma0(0);
    rdA0(1, 1, 1); rdB(1, 1, 1);
    mma1(0);
    WAIT_VM4();
    BARRIER();
    // s4: consume bank1 = (1,1)=o.kh1 | fill bank0 <- (0,0)=e' | stage (1,0)<-o+2
    rdA1(1, 1);
    stg(1, 0, to2);
    BARRIER();
    mma0(1);
    rdA0(0, 0, 0); rdB(0, 0, 0);
    mma1(1);
    WAIT_VM4();
    BARRIER();
  }

  // drain remaining lds-DMA before epilogue/endpgm (LDS may be reallocated).
  asm volatile("s_waitcnt vmcnt(0)" ::: "memory");

  // epilogue: C/D layout row = quad*4+v, col = l16 per 16x16 fragment
#pragma unroll
  for (int mt = 0; mt < 8; ++mt)
#pragma unroll
    for (int nt = 0; nt < 4; ++nt)
#pragma unroll
      for (int v = 0; v < 4; ++v) {
        int row = bm + wm + mt * 16 + quad * 4 + v;
        int col = bn + wn + nt * 16 + l16;
        if (vtout) {
          // row = b*S+s, col = h*128+d -> Vt[((b*16+h)*128+d)*S + s]
          size_t o = (size_t)(((row >> 11) * 16 + (col >> 7)) * 128 + (col & 127)) * S_ +
                     (row & 2047);
          C[o] = (TC)acc[mt][nt][v];
        } else {
          C[(size_t)row * DM_ + col] = (TC)acc[mt][nt][v];
        }
      }
}

// fused Q/K/V projection: 768 blocks; seg = bid>>8 picks weight + output.
__global__ __launch_bounds__(512, 2) void qkv_gemm(
    const bf16_t* __restrict__ xb, const bf16_t* __restrict__ wq,
    const bf16_t* __restrict__ wk, const bf16_t* __restrict__ wv,
    bf16_t* __restrict__ Qb, bf16_t* __restrict__ Kb, bf16_t* __restrict__ Vt) {
  __shared__ bf16_t Ab[2][2][8192];
  __shared__ bf16_t Bb[2][2][8192];
  const int seg  = (int)blockIdx.x >> 8;
  const int b256 = (int)blockIdx.x & 255;
  const bf16_t* W = (seg == 0) ? wq : (seg == 1) ? wk : wv;
  bf16_t* C       = (seg == 0) ? Qb : (seg == 1) ? Kb : Vt;
  gemm_body<bf16_t>(xb, W, C, seg == 2, b256, Ab, Bb);
}

// output projection: fp32 C.
__global__ __launch_bounds__(512, 2) void out_gemm(
    const bf16_t* __restrict__ Ob, const bf16_t* __restrict__ Wob,
    float* __restrict__ out) {
  __shared__ bf16_t Ab[2][2][8192];
  __shared__ bf16_t Bb[2][2][8192];
  gemm_body<float>(Ob, Wob, out, false, (int)blockIdx.x, Ab, Bb);
}

// ---------------------------------------------------------------------------
// Flash attention, dual-chain load-balanced version (measured 153.9 us r5):
//  * One workgroup owns TWO q-blocks {qa=31-p, qc=p}: constant 33 work-units.
//  * Both chains consume the SAME staged K/V tile (shared kf/vf ds_reads).
//  * K/V double-buffered, global_load_lds issued one tile ahead.
//  * XOR-swizzled LDS, inverse-swizzled global sources.
//  * DPP row_ror softmax reductions; Q direct global->reg; defer-max; setprio.
// LDS: Ks 32K + Vs 32K + Ps 16K = 80KB -> 2 blocks/CU.
// Q,K: [b*S+s][h*128+d] bf16.  VT: [(b*16+h)*128+d][s] bf16.  O like Q.
// ---------------------------------------------------------------------------
__global__ __launch_bounds__(256, 2) void attn_kernel(const bf16_t* __restrict__ Q,
                                                      const bf16_t* __restrict__ K,
                                                      const bf16_t* __restrict__ VT,
                                                      bf16_t* __restrict__ O,
                                                      const int* __restrict__ use_mask) {
  __shared__ bf16_t Ks[2 * 64 * 128];   // [buf][k][d], XOR-swizzled
  __shared__ bf16_t Vs[2 * 128 * 64];   // [buf][d][k], XOR-swizzled
  __shared__ bf16_t Ps[2 * 4 * 16 * 64];// [chain][wave][16][64], XOR-swizzled

  const int tid  = threadIdx.x;
  const int wave = tid >> 6;
  const int lane = tid & 63;
  const int quad = lane >> 4;
  const int l16  = lane & 15;

  const int lid  = (int)(blockIdx.y * gridDim.x + blockIdx.x);
  const int xcd  = lid & 7;
  const int t8   = lid >> 3;                 // 0..127
  const int bh   = xcd + ((t8 >> 4) << 3);   // 8 heads per XCD
  const int pair = t8 & 15;
  const int qa   = 31 - pair;                // heavy q-block (17..32 tiles)
  const int qc   = pair;                     // light q-block (1..16 tiles)
  const int b = bh >> 4, h = bh & 15;
  const int maskflag = *use_mask;

  const size_t qbaseA = ((size_t)b * S_ + (size_t)qa * 64) * DM_ + h * DK_;
  const size_t qbaseC = ((size_t)b * S_ + (size_t)qc * 64) * DM_ + h * DK_;

  int skO[4], svO[4];
#pragma unroll
  for (int p = 0; p < 4; ++p) {
    int rK = p * 16 + wave * 4 + quad;
    skO[p] = rK * DM_ + ((l16 ^ (rK & 7)) * 8);
    int dV = p * 32 + wave * 8 + (lane >> 3);
    svO[p] = dV * S_ + (((lane & 7) ^ (dV & 7)) * 8);
  }

  const bf16_t* Kbase = K + (size_t)b * S_ * DM_ + h * DK_;
  const bf16_t* Vbase = VT + (size_t)bh * DK_ * S_;

  auto stage_kv = [&](int j, int buf) __attribute__((always_inline)) {
    const bf16_t* kb = Kbase + (size_t)j * 64 * DM_;
    const bf16_t* vb = Vbase + (size_t)j * 64;
    bf16_t* kl = Ks + buf * 8192 + wave * 512;
    bf16_t* vl = Vs + buf * 8192 + wave * 512;
#pragma unroll
    for (int p = 0; p < 4; ++p) {
      async_copy16(kb + skO[p], kl + p * 2048);
      async_copy16(vb + svO[p], vl + p * 2048);
    }
  };

  bf16x8 qfA[4], qfC[4];
#pragma unroll
  for (int kk = 0; kk < 4; ++kk) {
    size_t ro = (size_t)(wave * 16 + l16) * DM_ + kk * 32 + quad * 8;
    qfA[kk] = *(const bf16x8*)(Q + qbaseA + ro);
    qfC[kk] = *(const bf16x8*)(Q + qbaseC + ro);
  }

  stage_kv(0, 0);

  f32x4 accA[8], accC[8];
#pragma unroll
  for (int i = 0; i < 8; ++i) {
    accA[i] = (f32x4){0.f, 0.f, 0.f, 0.f};
    accC[i] = (f32x4){0.f, 0.f, 0.f, 0.f};
  }
  float mA[4], lA[4], mC[4], lC[4];
#pragma unroll
  for (int v = 0; v < 4; ++v) {
    mA[v] = -INFINITY; lA[v] = 0.f;
    mC[v] = -INFINITY; lC[v] = 0.f;
  }

  bf16_t* PwA = Ps + wave * 1024;
  bf16_t* PwC = Ps + 4096 + wave * 1024;

  const float c1 = 0.08838834764831845f * 1.4426950408889634f;

  const int ntA = maskflag ? qa + 1 : (S_ / 64);
  const int ntC = maskflag ? qc + 1 : (S_ / 64);

  auto softmax_chain = [&](f32x4 (&s)[4], float (&mrow)[4], float (&lrow)[4],
                           f32x4 (&acc)[8], bf16_t* Pw, bool masked)
      __attribute__((always_inline)) {
#pragma unroll
    for (int v = 0; v < 4; ++v) {
      float x[4];
#pragma unroll
      for (int nt = 0; nt < 4; ++nt) {
        float y = s[nt][v] * c1;
        if (masked) {
          int kg = nt * 16 + l16;
          int qg = wave * 16 + quad * 4 + v;
          if (kg > qg) y = -INFINITY;
        }
        x[nt] = y;
      }
      float r = fmaxf(fmaxf(x[0], x[1]), fmaxf(x[2], x[3]));
      r = rowmax16(r);
      float m = mrow[v];
      if (r > m + 8.f) {
        float alpha = __builtin_amdgcn_exp2f(m - r);
        lrow[v] *= alpha;
#pragma unroll
        for (int dt = 0; dt < 8; ++dt) acc[dt][v] *= alpha;
        mrow[v] = r;
        m = r;
      }
      float rs = 0.f;
      int prow = quad * 4 + v;
#pragma unroll
      for (int nt = 0; nt < 4; ++nt) {
        float p = __builtin_amdgcn_exp2f(x[nt] - m);
        rs += p;
        Pw[prow * 64 + ((nt * 16 + l16) ^ ((prow & 7) << 3))] = (bf16_t)p;
      }
      lrow[v] += rowsum16(rs);
    }
  };

  auto body = [&](auto DOC, int cur, bool maskedA, bool maskedC)
      __attribute__((always_inline)) {
    constexpr bool doC = decltype(DOC)::v;
    const bf16_t* KsB = Ks + cur * 8192;
    const bf16_t* VsB = Vs + cur * 8192;

    f32x4 sA[4], sC[4];
#pragma unroll
    for (int nt = 0; nt < 4; ++nt) {
      sA[nt] = (f32x4){0.f, 0.f, 0.f, 0.f};
      sC[nt] = (f32x4){0.f, 0.f, 0.f, 0.f};
    }
    __builtin_amdgcn_s_setprio(1);
#pragma unroll
    for (int kk = 0; kk < 4; ++kk) {
#pragma unroll
      for (int nt = 0; nt < 4; ++nt) {
        bf16x8 kf = *(const bf16x8*)(KsB + (nt * 16 + l16) * 128 +
                                     ((kk * 32 + quad * 8) ^ ((l16 & 7) << 3)));
        sA[nt] = mfma16(qfA[kk], kf, sA[nt]);
        if constexpr (doC) sC[nt] = mfma16(qfC[kk], kf, sC[nt]);
      }
    }
    __builtin_amdgcn_s_setprio(0);

    softmax_chain(sA, mA, lA, accA, PwA, maskedA);
    if constexpr (doC) softmax_chain(sC, mC, lC, accC, PwC, maskedC);

    __builtin_amdgcn_s_setprio(1);
#pragma unroll
    for (int kk = 0; kk < 2; ++kk) {
      bf16x8 pfA = *(const bf16x8*)(PwA + l16 * 64 +
                                    ((kk * 32 + quad * 8) ^ ((l16 & 7) << 3)));
      bf16x8 pfC = {};
      if constexpr (doC)
        pfC = *(const bf16x8*)(PwC + l16 * 64 +
                               ((kk * 32 + quad * 8) ^ ((l16 & 7) << 3)));
#pragma unroll
      for (int dt = 0; dt < 8; ++dt) {
        bf16x8 vf = *(const bf16x8*)(VsB + (dt * 16 + l16) * 64 +
                                     ((kk * 32 + quad * 8) ^ ((l16 & 7) << 3)));
        accA[dt] = mfma16(pfA, vf, accA[dt]);
        if constexpr (doC) accC[dt] = mfma16(pfC, vf, accC[dt]);
      }
    }
    __builtin_amdgcn_s_setprio(0);
  };

  __syncthreads();

  for (int t = 0; t < ntA; ++t) {
    const int cur = t & 1;
    if (t + 1 < ntA) stage_kv(t + 1, cur ^ 1);
    const bool mAf = maskflag && (t == qa);
    if (t < ntC)
      body(ChainOn{},  cur, mAf, maskflag && (t == qc));
    else
      body(ChainOff{}, cur, mAf, false);
    __syncthreads();
  }

  auto epilogue = [&](f32x4 (&acc)[8], float (&lrow)[4], size_t qbase)
      __attribute__((always_inline)) {
    float rl[4];
#pragma unroll
    for (int v = 0; v < 4; ++v) rl[v] = __builtin_amdgcn_rcpf(lrow[v]);
#pragma unroll
    for (int dt = 0; dt < 8; ++dt)
#pragma unroll
      for (int v = 0; v < 4; ++v) {
        int qr = wave * 16 + quad * 4 + v;
        O[qbase + (size_t)qr * DM_ + dt * 16 + l16] = (bf16_t)(acc[dt][v] * rl[v]);
      }
  };
  epilogue(accA, lA, qbaseA);
  epilogue(accC, lC, qbaseC);
}

// ---------------------------------------------------------------------------
extern "C" void kernel_launch(void* const* d_in, const int* in_sizes, int n_in,
                              void* d_out, int out_size, void* d_ws, size_t ws_size,
                              hipStream_t stream) {
  const float* x  = (const float*)d_in[0];
  const float* Wq = (const float*)d_in[1];
  const float* Wk = (const float*)d_in[2];
  const float* Wv = (const float*)d_in[3];
  const float* Wo = (const float*)d_in[4];
  const int* use_mask = (const int*)d_in[5];
  float* out = (float*)d_out;

  const size_t TSZ = (size_t)BS_ * DM_;   // 16,777,216 elems (32 MiB bf16)
  const size_t WSZ = (size_t)DM_ * DM_;   //  4,194,304 elems ( 8 MiB bf16)
  bf16_t* Qb  = (bf16_t*)d_ws;            // R0
  bf16_t* Kb  = Qb + TSZ;                 // R1
  bf16_t* Vt  = Kb + TSZ;                 // R2: Vt, then Wo_bf16 after attention
  bf16_t* xb  = Vt + TSZ;                 // R3: x_bf16, then Ob after projections
  bf16_t* Ob  = xb;
  bf16_t* Wob = Vt;
  // weight bf16 staging inside d_out (64 MiB fp32; fully overwritten at the end)
  bf16_t* wq = (bf16_t*)d_out;
  bf16_t* wk = wq + WSZ;
  bf16_t* wv = wk + WSZ;

  cvt_bf16<<<(int)(TSZ / 8 / 256), 256, 0, stream>>>(x,  xb, (int)(TSZ / 8));
  cvt_bf16<<<(int)(WSZ / 8 / 256), 256, 0, stream>>>(Wq, wq, (int)(WSZ / 8));
  cvt_bf16<<<(int)(WSZ / 8 / 256), 256, 0, stream>>>(Wk, wk, (int)(WSZ / 8));
  cvt_bf16<<<(int)(WSZ / 8 / 256), 256, 0, stream>>>(Wv, wv, (int)(WSZ / 8));

  qkv_gemm<<<dim3(768), 512, 0, stream>>>(xb, wq, wk, wv, Qb, Kb, Vt);

  dim3 gA(16, 64);                   // 1024 balanced dual-q blocks
  attn_kernel<<<gA, 256, 0, stream>>>(Qb, Kb, Vt, Ob, use_mask);

  cvt_bf16<<<(int)(WSZ / 8 / 256), 256, 0, stream>>>(Wo, Wob, (int)(WSZ / 8));
  out_gemm<<<dim3(256), 512, 0, stream>>>(Ob, Wob, out);
}

// Round 12
// 584.251 us; speedup vs baseline: 1.0128x; 1.0128x over previous
//
#include <hip/hip_runtime.h>
#include <hip/hip_bf16.h>

typedef __bf16 bf16_t;
typedef __bf16 bf16x8 __attribute__((ext_vector_type(8)));
typedef float f32x4 __attribute__((ext_vector_type(4)));

#define B_  4
#define S_  2048
#define H_  16
#define DK_ 128
#define DM_ 2048
#define BS_ (B_ * S_)          // 8192 rows

static __device__ __forceinline__ f32x4 mfma16(bf16x8 a, bf16x8 b, f32x4 c) {
  return __builtin_amdgcn_mfma_f32_16x16x32_bf16(a, b, c, 0, 0, 0);
}

// async global->LDS 16B copy. lds base must be wave-uniform; HW scatters lane*16.
static __device__ __forceinline__ void async_copy16(const bf16_t* g, bf16_t* l) {
  __builtin_amdgcn_global_load_lds(
      (const __attribute__((address_space(1))) void*)g,
      (__attribute__((address_space(3))) void*)l, 16, 0, 0);
}

// raw workgroup barrier WITHOUT the vmcnt(0)/lgkmcnt(0) drain __syncthreads
// emits; "memory" clobber = compiler fence.
#define BARRIER() asm volatile("s_barrier" ::: "memory")
#define WAIT_VM2() asm volatile("s_waitcnt vmcnt(2)" ::: "memory")

// DPP row_ror (within 16-lane row) on f32 -- cross-lane reduce on the VALU pipe.
template <int CTRL>
static __device__ __forceinline__ float dpp_rorf(float x) {
  return __builtin_bit_cast(float,
      __builtin_amdgcn_update_dpp(0, __builtin_bit_cast(int, x), CTRL, 0xF, 0xF, true));
}
static __device__ __forceinline__ float rowmax16(float r) {
  r = fmaxf(r, dpp_rorf<0x121>(r));
  r = fmaxf(r, dpp_rorf<0x122>(r));
  r = fmaxf(r, dpp_rorf<0x124>(r));
  r = fmaxf(r, dpp_rorf<0x128>(r));
  return r;
}
static __device__ __forceinline__ float rowsum16(float r) {
  r += dpp_rorf<0x121>(r);
  r += dpp_rorf<0x122>(r);
  r += dpp_rorf<0x124>(r);
  r += dpp_rorf<0x128>(r);
  return r;
}

struct ChainOn  { static constexpr bool v = true;  };
struct ChainOff { static constexpr bool v = false; };

// ---------------------------------------------------------------------------
// fp32 -> bf16 elementwise convert (8 elems/thread)
// ---------------------------------------------------------------------------
__global__ __launch_bounds__(256) void cvt_bf16(const float* __restrict__ in,
                                                bf16_t* __restrict__ out, int n8) {
  int i = blockIdx.x * 256 + threadIdx.x;
  if (i < n8) {
    const float4* p = (const float4*)in + (size_t)i * 2;
    float4 f0 = p[0], f1 = p[1];
    bf16x8 r;
    r[0] = (bf16_t)f0.x; r[1] = (bf16_t)f0.y; r[2] = (bf16_t)f0.z; r[3] = (bf16_t)f0.w;
    r[4] = (bf16_t)f1.x; r[5] = (bf16_t)f1.y; r[6] = (bf16_t)f1.z; r[7] = (bf16_t)f1.w;
    ((bf16x8*)out)[i] = r;
  }
}

// ---------------------------------------------------------------------------
// GEMM body: C[M,N] = A[M,K] * B[N,K]^T, 256x256 tile, BK=64, 8 waves (2Mx4N),
// m201-faithful LDS organization (r11 post-mortem: my swizzle measured 70x
// m201's bank conflicts; schedule variants r9-r11 all null at ~37% MfmaUtil).
//  * Half-tiles split by ROWS: [dbuf][half][128 rows][64 cols] per operand.
//  * st_16x32 swizzle: byte ^= ((byte>>9)&1)<<5  ==  elem-bit-4 ^= row-bit-2.
//    LDS dest stays LINEAR for global_load_lds; the per-lane global SOURCE
//    col-chunk is inverse-swizzled (gc ^= (row>>2&1)<<1, 8-elem granules);
//    every ds_read applies the same XOR (rule #21 both-sides).
//  * 8 phases/iter (iter = tiles e=2I buf0, o=2I+1 buf1). Quadrant order
//    (m0n0)(m0n1)(m1n0)(m1n1) per tile; A-quad (8 b128) and B-quad (4 b128)
//    fragments held across phases -> reads/phase = 12,4,8,0.
//  * Phase: {ds_read | stage 1 half (2 loads/thread) | BAR1 | 16 MFMA | BAR2}.
//  * Counted vmcnt(2) ONLY at end-p4 and end-p8 (before BAR2), never 0.
//
// Ledger (FIFO, 2 instr/stage; stages p1:A1h1<-o p2:B1h0<-o p3:B1h1<-o
// p4:A0h0<-e2 p5:A0h1<-e2 p6:B0h0<-e2 p7:B0h1<-e2 p8:A1h0<-o2):
//  end-p4 wait: outstanding {I-1.p8, p1..p4} = 10 instr -> vmcnt(2) drains
//   through p3 = ALL of buf1<-o (read p5-p7), leaves p4. Flight >= 1.5 phases.
//  end-p8 wait: outstanding {p4..p8} = 10 -> drains through p7 = ALL of
//   buf0<-e2 (read next p1-p3), leaves p8. Flight 1.5-4 phases >> HBM ~900cyc.
//  Waits precede BAR2, so every wave's loads are confirmed before any wave's
//  dependent ds_read next phase.
// Overwrite safety (>=1 barrier-pair between last read and stage, all 8):
//  A1h1 read I-1.p7 / staged I.p1; B1h0 read I-1.p6(w0,1 nq1=rows 32-63/96-127
//  resp) / staged I.p2; B1h1 read I-1.p6 / staged I.p3; A0h0,A0h1 read I.p3 /
//  staged I.p4,p5; B0h0,B0h1 read I.p2 / staged I.p6,p7; A1h0 read I.p7 /
//  staged I.p8.
// Prologue: stage buf0(4 halves)<-t0 + A1h0<-t1; vmcnt(2) drains buf0 exactly,
// leaving A1h0 in its steady p8 slot. Tail: e2,o2 clamp to NT-1 (dead slots);
// final vmcnt(0) before epilogue (LDS may be reallocated).
// vtout: write C per-head-transposed into Vt layout [(b*16+h)*128+d][s].
// ---------------------------------------------------------------------------
template <typename TC>
static __device__ __forceinline__ void gemm_body(
    const bf16_t* __restrict__ A, const bf16_t* __restrict__ B, TC* __restrict__ C,
    bool vtout, int b256, bf16_t (&Ab)[2][2][8192], bf16_t (&Bb)[2][2][8192]) {
  const int tid  = threadIdx.x;
  const int wave = tid >> 6;              // 0..7
  const int lane = tid & 63;
  const int quad = lane >> 4;
  const int l16  = lane & 15;
  const int wm    = (wave >> 2) * 128;    // wave's M rows (A-half = wave>>2)
  const int wn    = (wave & 3) * 64;      // wave's N cols
  const int mhalf = wave >> 2;            // wave's A-half
  const int nhalf = (wave & 3) >> 1;      // wave's B-half
  const int nrow0 = (wave & 1) * 64;      // row base within the B-half

  // XCD-bijective remap: 256 blocks; each xcd owns a contiguous 4x8 stripe.
  const int xcd = b256 & 7;
  const int idx = b256 >> 3;              // 0..31
  const int bm  = (xcd * 4 + (idx >> 3)) * 256;
  const int bn  = (idx & 7) * 256;
  const int K   = DM_;

  const bf16_t* Ablk = A + (size_t)bm * (size_t)K;
  const bf16_t* Bblk = B + (size_t)bn * (size_t)K;

  // staging geometry: half-tile = 128x64; granule g = i*512 + wave*64 + lane
  // covers phys elems [g*8, g*8+8). row = g>>3, chunk gc = g&7. Source chunk
  // inverse-swizzled: gc ^ ((row>>2)&1)<<1.
  int srcO[2];
#pragma unroll
  for (int i = 0; i < 2; ++i) {
    int g = i * 512 + wave * 64 + lane;
    int row = g >> 3, gc = g & 7;
    srcO[i] = row * K + ((gc ^ (((row >> 2) & 1) << 1)) * 8);
  }
  const int dstO0 = wave * 512;           // wave-uniform LDS elem bases
  const int dstO1 = 4096 + wave * 512;

  auto stgA = [&](int buf, int half, int kt) __attribute__((always_inline)) {
    const bf16_t* src = Ablk + (size_t)(half * 128) * K + kt * 64;
    async_copy16(src + srcO[0], &Ab[buf][half][dstO0]);
    async_copy16(src + srcO[1], &Ab[buf][half][dstO1]);
  };
  auto stgB = [&](int buf, int half, int kt) __attribute__((always_inline)) {
    const bf16_t* src = Bblk + (size_t)(half * 128) * K + kt * 64;
    async_copy16(src + srcO[0], &Bb[buf][half][dstO0]);
    async_copy16(src + srcO[1], &Bb[buf][half][dstO1]);
  };

  f32x4 acc[8][4];
#pragma unroll
  for (int i = 0; i < 8; ++i)
#pragma unroll
    for (int j = 0; j < 4; ++j) acc[i][j] = (f32x4){0.f, 0.f, 0.f, 0.f};

  bf16x8 af[8], bf0[4], bf1[4];

  // A quadrant mq: 4 M-frags x K=64 (2 chunks). Row within half; st_16x32
  // read XOR = ((row>>2)&1)<<4 on the elem index.
  auto rdA = [&](int buf, int mq) __attribute__((always_inline)) {
#pragma unroll
    for (int mf = 0; mf < 4; ++mf) {
      int row = mq * 64 + mf * 16 + l16;
      int sw  = ((row >> 2) & 1) << 4;
#pragma unroll
      for (int kk = 0; kk < 2; ++kk)
        af[mf * 2 + kk] =
            *(const bf16x8*)(&Ab[buf][mhalf][(row * 64 + kk * 32 + quad * 8) ^ sw]);
    }
  };
  // B quadrant nq: 2 N-frags x K=64.
  auto rdB = [&](bf16x8 (&dst)[4], int buf, int nq) __attribute__((always_inline)) {
#pragma unroll
    for (int nf = 0; nf < 2; ++nf) {
      int row = nrow0 + nq * 32 + nf * 16 + l16;
      int sw  = ((row >> 2) & 1) << 4;
#pragma unroll
      for (int kk = 0; kk < 2; ++kk)
        dst[nf * 2 + kk] =
            *(const bf16x8*)(&Bb[buf][nhalf][(row * 64 + kk * 32 + quad * 8) ^ sw]);
    }
  };
  auto mmaq = [&](int mq, int nq, bf16x8 (&bq)[4]) __attribute__((always_inline)) {
    __builtin_amdgcn_s_setprio(1);
#pragma unroll
    for (int mf = 0; mf < 4; ++mf)
#pragma unroll
      for (int nf = 0; nf < 2; ++nf)
#pragma unroll
        for (int kk = 0; kk < 2; ++kk)
          acc[mq * 4 + mf][nq * 2 + nf] =
              mfma16(af[mf * 2 + kk], bq[nf * 2 + kk], acc[mq * 4 + mf][nq * 2 + nf]);
    __builtin_amdgcn_s_setprio(0);
  };

  const int NT    = K >> 6;               // 32 K-tiles (BK=64)
  const int ITERS = NT >> 1;              // 16 iters (2 K-tiles each)

  // prologue: buf0 <- t0 (4 halves) + buf1.A-h0 <- t1; drain buf0 exactly.
  stgA(0, 0, 0); stgA(0, 1, 0); stgB(0, 0, 0); stgB(0, 1, 0);
  stgA(1, 0, 1);
  WAIT_VM2();
  BARRIER();

  for (int I = 0; I < ITERS; ++I) {
    const int o  = 2 * I + 1;
    const int e2 = (2 * I + 2 < NT) ? 2 * I + 2 : NT - 1;   // clamped tail
    const int o2 = (2 * I + 3 < NT) ? 2 * I + 3 : NT - 1;

    // p1: reads e.(A-mq0, B-nq0) [12] | stage buf1.A-h1 <- o
    rdA(0, 0); rdB(bf0, 0, 0);
    stgA(1, 1, o);
    BARRIER();
    mmaq(0, 0, bf0);
    BARRIER();
    // p2: reads e.B-nq1 [4] | stage buf1.B-h0 <- o
    rdB(bf1, 0, 1);
    stgB(1, 0, o);
    BARRIER();
    mmaq(0, 1, bf1);
    BARRIER();
    // p3: reads e.A-mq1 [8] | stage buf1.B-h1 <- o
    rdA(0, 1);
    stgB(1, 1, o);
    BARRIER();
    mmaq(1, 0, bf0);
    BARRIER();
    // p4: no reads | stage buf0.A-h0 <- e+2 | WAIT (drains all of buf1<-o)
    stgA(0, 0, e2);
    BARRIER();
    mmaq(1, 1, bf1);
    WAIT_VM2();
    BARRIER();
    // p5: reads o.(A-mq0, B-nq0) [12] | stage buf0.A-h1 <- e+2
    rdA(1, 0); rdB(bf0, 1, 0);
    stgA(0, 1, e2);
    BARRIER();
    mmaq(0, 0, bf0);
    BARRIER();
    // p6: reads o.B-nq1 [4] | stage buf0.B-h0 <- e+2
    rdB(bf1, 1, 1);
    stgB(0, 0, e2);
    BARRIER();
    mmaq(0, 1, bf1);
    BARRIER();
    // p7: reads o.A-mq1 [8] | stage buf0.B-h1 <- e+2
    rdA(1, 1);
    stgB(0, 1, e2);
    BARRIER();
    mmaq(1, 0, bf0);
    BARRIER();
    // p8: no reads | stage buf1.A-h0 <- o+2 | WAIT (drains all of buf0<-e+2)
    stgA(1, 0, o2);
    BARRIER();
    mmaq(1, 1, bf1);
    WAIT_VM2();
    BARRIER();
  }

  // drain remaining lds-DMA before epilogue/endpgm (LDS may be reallocated).
  asm volatile("s_waitcnt vmcnt(0)" ::: "memory");

  // epilogue: C/D layout row = quad*4+v, col = l16 per 16x16 fragment
#pragma unroll
  for (int mt = 0; mt < 8; ++mt)
#pragma unroll
    for (int nt = 0; nt < 4; ++nt)
#pragma unroll
      for (int v = 0; v < 4; ++v) {
        int row = bm + wm + mt * 16 + quad * 4 + v;
        int col = bn + wn + nt * 16 + l16;
        if (vtout) {
          // row = b*S+s, col = h*128+d -> Vt[((b*16+h)*128+d)*S + s]
          size_t o = (size_t)(((row >> 11) * 16 + (col >> 7)) * 128 + (col & 127)) * S_ +
                     (row & 2047);
          C[o] = (TC)acc[mt][nt][v];
        } else {
          C[(size_t)row * DM_ + col] = (TC)acc[mt][nt][v];
        }
      }
}

// fused Q/K/V projection: 768 blocks; seg = bid>>8 picks weight + output.
__global__ __launch_bounds__(512, 2) void qkv_gemm(
    const bf16_t* __restrict__ xb, const bf16_t* __restrict__ wq,
    const bf16_t* __restrict__ wk, const bf16_t* __restrict__ wv,
    bf16_t* __restrict__ Qb, bf16_t* __restrict__ Kb, bf16_t* __restrict__ Vt) {
  __shared__ bf16_t Ab[2][2][8192];
  __shared__ bf16_t Bb[2][2][8192];
  const int seg  = (int)blockIdx.x >> 8;
  const int b256 = (int)blockIdx.x & 255;
  const bf16_t* W = (seg == 0) ? wq : (seg == 1) ? wk : wv;
  bf16_t* C       = (seg == 0) ? Qb : (seg == 1) ? Kb : Vt;
  gemm_body<bf16_t>(xb, W, C, seg == 2, b256, Ab, Bb);
}

// output projection: fp32 C.
__global__ __launch_bounds__(512, 2) void out_gemm(
    const bf16_t* __restrict__ Ob, const bf16_t* __restrict__ Wob,
    float* __restrict__ out) {
  __shared__ bf16_t Ab[2][2][8192];
  __shared__ bf16_t Bb[2][2][8192];
  gemm_body<float>(Ob, Wob, out, false, (int)blockIdx.x, Ab, Bb);
}

// ---------------------------------------------------------------------------
// Flash attention, dual-chain load-balanced version (measured 153.9 us r5):
//  * One workgroup owns TWO q-blocks {qa=31-p, qc=p}: constant 33 work-units.
//  * Both chains consume the SAME staged K/V tile (shared kf/vf ds_reads).
//  * K/V double-buffered, global_load_lds issued one tile ahead.
//  * XOR-swizzled LDS, inverse-swizzled global sources.
//  * DPP row_ror softmax reductions; Q direct global->reg; defer-max; setprio.
// LDS: Ks 32K + Vs 32K + Ps 16K = 80KB -> 2 blocks/CU.
// Q,K: [b*S+s][h*128+d] bf16.  VT: [(b*16+h)*128+d][s] bf16.  O like Q.
// ---------------------------------------------------------------------------
__global__ __launch_bounds__(256, 2) void attn_kernel(const bf16_t* __restrict__ Q,
                                                      const bf16_t* __restrict__ K,
                                                      const bf16_t* __restrict__ VT,
                                                      bf16_t* __restrict__ O,
                                                      const int* __restrict__ use_mask) {
  __shared__ bf16_t Ks[2 * 64 * 128];   // [buf][k][d], XOR-swizzled
  __shared__ bf16_t Vs[2 * 128 * 64];   // [buf][d][k], XOR-swizzled
  __shared__ bf16_t Ps[2 * 4 * 16 * 64];// [chain][wave][16][64], XOR-swizzled

  const int tid  = threadIdx.x;
  const int wave = tid >> 6;
  const int lane = tid & 63;
  const int quad = lane >> 4;
  const int l16  = lane & 15;

  const int lid  = (int)(blockIdx.y * gridDim.x + blockIdx.x);
  const int xcd  = lid & 7;
  const int t8   = lid >> 3;                 // 0..127
  const int bh   = xcd + ((t8 >> 4) << 3);   // 8 heads per XCD
  const int pair = t8 & 15;
  const int qa   = 31 - pair;                // heavy q-block (17..32 tiles)
  const int qc   = pair;                     // light q-block (1..16 tiles)
  const int b = bh >> 4, h = bh & 15;
  const int maskflag = *use_mask;

  const size_t qbaseA = ((size_t)b * S_ + (size_t)qa * 64) * DM_ + h * DK_;
  const size_t qbaseC = ((size_t)b * S_ + (size_t)qc * 64) * DM_ + h * DK_;

  int skO[4], svO[4];
#pragma unroll
  for (int p = 0; p < 4; ++p) {
    int rK = p * 16 + wave * 4 + quad;
    skO[p] = rK * DM_ + ((l16 ^ (rK & 7)) * 8);
    int dV = p * 32 + wave * 8 + (lane >> 3);
    svO[p] = dV * S_ + (((lane & 7) ^ (dV & 7)) * 8);
  }

  const bf16_t* Kbase = K + (size_t)b * S_ * DM_ + h * DK_;
  const bf16_t* Vbase = VT + (size_t)bh * DK_ * S_;

  auto stage_kv = [&](int j, int buf) __attribute__((always_inline)) {
    const bf16_t* kb = Kbase + (size_t)j * 64 * DM_;
    const bf16_t* vb = Vbase + (size_t)j * 64;
    bf16_t* kl = Ks + buf * 8192 + wave * 512;
    bf16_t* vl = Vs + buf * 8192 + wave * 512;
#pragma unroll
    for (int p = 0; p < 4; ++p) {
      async_copy16(kb + skO[p], kl + p * 2048);
      async_copy16(vb + svO[p], vl + p * 2048);
    }
  };

  bf16x8 qfA[4], qfC[4];
#pragma unroll
  for (int kk = 0; kk < 4; ++kk) {
    size_t ro = (size_t)(wave * 16 + l16) * DM_ + kk * 32 + quad * 8;
    qfA[kk] = *(const bf16x8*)(Q + qbaseA + ro);
    qfC[kk] = *(const bf16x8*)(Q + qbaseC + ro);
  }

  stage_kv(0, 0);

  f32x4 accA[8], accC[8];
#pragma unroll
  for (int i = 0; i < 8; ++i) {
    accA[i] = (f32x4){0.f, 0.f, 0.f, 0.f};
    accC[i] = (f32x4){0.f, 0.f, 0.f, 0.f};
  }
  float mA[4], lA[4], mC[4], lC[4];
#pragma unroll
  for (int v = 0; v < 4; ++v) {
    mA[v] = -INFINITY; lA[v] = 0.f;
    mC[v] = -INFINITY; lC[v] = 0.f;
  }

  bf16_t* PwA = Ps + wave * 1024;
  bf16_t* PwC = Ps + 4096 + wave * 1024;

  const float c1 = 0.08838834764831845f * 1.4426950408889634f;

  const int ntA = maskflag ? qa + 1 : (S_ / 64);
  const int ntC = maskflag ? qc + 1 : (S_ / 64);

  auto softmax_chain = [&](f32x4 (&s)[4], float (&mrow)[4], float (&lrow)[4],
                           f32x4 (&acc)[8], bf16_t* Pw, bool masked)
      __attribute__((always_inline)) {
#pragma unroll
    for (int v = 0; v < 4; ++v) {
      float x[4];
#pragma unroll
      for (int nt = 0; nt < 4; ++nt) {
        float y = s[nt][v] * c1;
        if (masked) {
          int kg = nt * 16 + l16;
          int qg = wave * 16 + quad * 4 + v;
          if (kg > qg) y = -INFINITY;
        }
        x[nt] = y;
      }
      float r = fmaxf(fmaxf(x[0], x[1]), fmaxf(x[2], x[3]));
      r = rowmax16(r);
      float m = mrow[v];
      if (r > m + 8.f) {
        float alpha = __builtin_amdgcn_exp2f(m - r);
        lrow[v] *= alpha;
#pragma unroll
        for (int dt = 0; dt < 8; ++dt) acc[dt][v] *= alpha;
        mrow[v] = r;
        m = r;
      }
      float rs = 0.f;
      int prow = quad * 4 + v;
#pragma unroll
      for (int nt = 0; nt < 4; ++nt) {
        float p = __builtin_amdgcn_exp2f(x[nt] - m);
        rs += p;
        Pw[prow * 64 + ((nt * 16 + l16) ^ ((prow & 7) << 3))] = (bf16_t)p;
      }
      lrow[v] += rowsum16(rs);
    }
  };

  auto body = [&](auto DOC, int cur, bool maskedA, bool maskedC)
      __attribute__((always_inline)) {
    constexpr bool doC = decltype(DOC)::v;
    const bf16_t* KsB = Ks + cur * 8192;
    const bf16_t* VsB = Vs + cur * 8192;

    f32x4 sA[4], sC[4];
#pragma unroll
    for (int nt = 0; nt < 4; ++nt) {
      sA[nt] = (f32x4){0.f, 0.f, 0.f, 0.f};
      sC[nt] = (f32x4){0.f, 0.f, 0.f, 0.f};
    }
    __builtin_amdgcn_s_setprio(1);
#pragma unroll
    for (int kk = 0; kk < 4; ++kk) {
#pragma unroll
      for (int nt = 0; nt < 4; ++nt) {
        bf16x8 kf = *(const bf16x8*)(KsB + (nt * 16 + l16) * 128 +
                                     ((kk * 32 + quad * 8) ^ ((l16 & 7) << 3)));
        sA[nt] = mfma16(qfA[kk], kf, sA[nt]);
        if constexpr (doC) sC[nt] = mfma16(qfC[kk], kf, sC[nt]);
      }
    }
    __builtin_amdgcn_s_setprio(0);

    softmax_chain(sA, mA, lA, accA, PwA, maskedA);
    if constexpr (doC) softmax_chain(sC, mC, lC, accC, PwC, maskedC);

    __builtin_amdgcn_s_setprio(1);
#pragma unroll
    for (int kk = 0; kk < 2; ++kk) {
      bf16x8 pfA = *(const bf16x8*)(PwA + l16 * 64 +
                                    ((kk * 32 + quad * 8) ^ ((l16 & 7) << 3)));
      bf16x8 pfC = {};
      if constexpr (doC)
        pfC = *(const bf16x8*)(PwC + l16 * 64 +
                               ((kk * 32 + quad * 8) ^ ((l16 & 7) << 3)));
#pragma unroll
      for (int dt = 0; dt < 8; ++dt) {
        bf16x8 vf = *(const bf16x8*)(VsB + (dt * 16 + l16) * 64 +
                                     ((kk * 32 + quad * 8) ^ ((l16 & 7) << 3)));
        accA[dt] = mfma16(pfA, vf, accA[dt]);
        if constexpr (doC) accC[dt] = mfma16(pfC, vf, accC[dt]);
      }
    }
    __builtin_amdgcn_s_setprio(0);
  };

  __syncthreads();

  for (int t = 0; t < ntA; ++t) {
    const int cur = t & 1;
    if (t + 1 < ntA) stage_kv(t + 1, cur ^ 1);
    const bool mAf = maskflag && (t == qa);
    if (t < ntC)
      body(ChainOn{},  cur, mAf, maskflag && (t == qc));
    else
      body(ChainOff{}, cur, mAf, false);
    __syncthreads();
  }

  auto epilogue = [&](f32x4 (&acc)[8], float (&lrow)[4], size_t qbase)
      __attribute__((always_inline)) {
    float rl[4];
#pragma unroll
    for (int v = 0; v < 4; ++v) rl[v] = __builtin_amdgcn_rcpf(lrow[v]);
#pragma unroll
    for (int dt = 0; dt < 8; ++dt)
#pragma unroll
      for (int v = 0; v < 4; ++v) {
        int qr = wave * 16 + quad * 4 + v;
        O[qbase + (size_t)qr * DM_ + dt * 16 + l16] = (bf16_t)(acc[dt][v] * rl[v]);
      }
  };
  epilogue(accA, lA, qbaseA);
  epilogue(accC, lC, qbaseC);
}

// ---------------------------------------------------------------------------
extern "C" void kernel_launch(void* const* d_in, const int* in_sizes, int n_in,
                              void* d_out, int out_size, void* d_ws, size_t ws_size,
                              hipStream_t stream) {
  const float* x  = (const float*)d_in[0];
  const float* Wq = (const float*)d_in[1];
  const float* Wk = (const float*)d_in[2];
  const float* Wv = (const float*)d_in[3];
  const float* Wo = (const float*)d_in[4];
  const int* use_mask = (const int*)d_in[5];
  float* out = (float*)d_out;

  const size_t TSZ = (size_t)BS_ * DM_;   // 16,777,216 elems (32 MiB bf16)
  const size_t WSZ = (size_t)DM_ * DM_;   //  4,194,304 elems ( 8 MiB bf16)
  bf16_t* Qb  = (bf16_t*)d_ws;            // R0
  bf16_t* Kb  = Qb + TSZ;                 // R1
  bf16_t* Vt  = Kb + TSZ;                 // R2: Vt, then Wo_bf16 after attention
  bf16_t* xb  = Vt + TSZ;                 // R3: x_bf16, then Ob after projections
  bf16_t* Ob  = xb;
  bf16_t* Wob = Vt;
  // weight bf16 staging inside d_out (64 MiB fp32; fully overwritten at the end)
  bf16_t* wq = (bf16_t*)d_out;
  bf16_t* wk = wq + WSZ;
  bf16_t* wv = wk + WSZ;

  cvt_bf16<<<(int)(TSZ / 8 / 256), 256, 0, stream>>>(x,  xb, (int)(TSZ / 8));
  cvt_bf16<<<(int)(WSZ / 8 / 256), 256, 0, stream>>>(Wq, wq, (int)(WSZ / 8));
  cvt_bf16<<<(int)(WSZ / 8 / 256), 256, 0, stream>>>(Wk, wk, (int)(WSZ / 8));
  cvt_bf16<<<(int)(WSZ / 8 / 256), 256, 0, stream>>>(Wv, wv, (int)(WSZ / 8));

  qkv_gemm<<<dim3(768), 512, 0, stream>>>(xb, wq, wk, wv, Qb, Kb, Vt);

  dim3 gA(16, 64);                   // 1024 balanced dual-q blocks
  attn_kernel<<<gA, 256, 0, stream>>>(Qb, Kb, Vt, Ob, use_mask);

  cvt_bf16<<<(int)(WSZ / 8 / 256), 256, 0, stream>>>(Wo, Wob, (int)(WSZ / 8));
  out_gemm<<<dim3(256), 512, 0, stream>>>(Ob, Wob, out);
}